// Round 8
// baseline (481.246 us; speedup 1.0000x reference)
//
#include <hip/hip_runtime.h>
#include <math.h>

// ---------------------------------------------------------------------------
// 2-layer GCN:  out = GCN2( relu(GCN1( softmax(x) )) )
// GCNi(h) = Agg( h @ Wi ) + bi  with  Agg_i = sum_{e: col=i} norm_e * (hW)[row_e]
// norm_e = dinv[row]*ew*dinv[col], dinv = rsqrt(deg), deg = indeg_w + 1 (self loop)
// Self-loop contribution handled analytically: dinv[i]^2 * (hW)[i].
// CSR (grouped by destination) rebuilt on-device every call (ws is re-poisoned).
// ROUND 6 FIX: edge_index arrives as INT32 (harness converts integer inputs
// to int; const long long* cast read 6.4MB past the buffer -> HSA access
// fault -> "Aborted (core dumped)"). Round 7 was an acquisition timeout;
// this is the unmeasured round-6 kernel resubmitted verbatim.
// ---------------------------------------------------------------------------

__global__ void softmax_kernel(const float* __restrict__ x, float* __restrict__ out,
                               int nrows) {
  int gid  = blockIdx.x * blockDim.x + threadIdx.x;
  int row  = gid >> 6;          // one wave (64 lanes) per row, 2 ch/lane
  int lane = gid & 63;
  if (row >= nrows) return;
  const float2* xr = reinterpret_cast<const float2*>(x + (size_t)row * 128);
  float2 v = xr[lane];
  float m = fmaxf(v.x, v.y);
#pragma unroll
  for (int o = 32; o > 0; o >>= 1) m = fmaxf(m, __shfl_xor(m, o));
  float e0 = expf(v.x - m), e1 = expf(v.y - m);
  float s = e0 + e1;
#pragma unroll
  for (int o = 32; o > 0; o >>= 1) s += __shfl_xor(s, o);
  float inv = 1.0f / s;
  float2 r; r.x = e0 * inv; r.y = e1 * inv;
  reinterpret_cast<float2*>(out + (size_t)row * 128)[lane] = r;
}

// deg_w[col] += ew ; counts[col] += 1   (self-loop added later as +1.0)
__global__ void deg_kernel(const int* __restrict__ ei, const float* __restrict__ ew,
                           float* __restrict__ deg_w, int* __restrict__ counts, int E) {
  int e = blockIdx.x * blockDim.x + threadIdx.x;
  if (e >= E) return;
  int c = ei[(size_t)E + e];
  atomicAdd(&deg_w[c], ew[e]);
  atomicAdd(&counts[c], 1);
}

__global__ void dinv_kernel(const float* __restrict__ deg_w, float* __restrict__ dinv,
                            int n) {
  int i = blockIdx.x * blockDim.x + threadIdx.x;
  if (i >= n) return;
  float d = deg_w[i] + 1.0f;       // + self loop weight
  dinv[i] = (d > 0.0f) ? (1.0f / sqrtf(d)) : 0.0f;
}

// single-block exclusive scan of counts[0..n) -> offs[0..n]
__global__ void scan_kernel(const int* __restrict__ counts, int* __restrict__ offs, int n) {
  __shared__ int sums[1024];
  int t = threadIdx.x;
  int chunk = (n + 1023) / 1024;
  int lo = t * chunk;
  int hi = lo + chunk; if (hi > n) hi = n;
  int s = 0;
  for (int i = lo; i < hi; ++i) s += counts[i];
  sums[t] = s;
  __syncthreads();
  for (int d = 1; d < 1024; d <<= 1) {
    int v = (t >= d) ? sums[t - d] : 0;
    __syncthreads();
    sums[t] += v;
    __syncthreads();
  }
  int run = (t == 0) ? 0 : sums[t - 1];
  for (int i = lo; i < hi; ++i) { offs[i] = run; run += counts[i]; }
  if (t == 1023) offs[n] = sums[1023];
}

__global__ void scatter_kernel(const int* __restrict__ ei, const float* __restrict__ ew,
                               const float* __restrict__ dinv, const int* __restrict__ offs,
                               int* __restrict__ cursor, int* __restrict__ csr_src,
                               float* __restrict__ csr_nrm, int E) {
  int e = blockIdx.x * blockDim.x + threadIdx.x;
  if (e >= E) return;
  int r = ei[e];
  int c = ei[(size_t)E + e];
  int pos = offs[c] + atomicAdd(&cursor[c], 1);
  csr_src[pos] = r;
  csr_nrm[pos] = dinv[r] * ew[e] * dinv[c];
}

// C = A(M x 128) @ W(128 x N), fp32, 4x4 register tile per thread, A tile in LDS
template <int N>
__global__ __launch_bounds__(256) void gemm_kernel(const float* __restrict__ A,
                                                   const float* __restrict__ W,
                                                   float* __restrict__ C, int M) {
  constexpr int CG  = N / 4;       // float4 column groups (32 or 16)
  constexpr int RG  = 256 / CG;    // row groups (8 or 16)
  constexpr int BM  = RG * 4;      // rows per block (32 or 64)
  constexpr int LDA = 132;         // padded to avoid bank conflicts
  __shared__ float sA[BM][LDA];
  const int t   = threadIdx.x;
  const int tx  = t % CG;
  const int ty  = t / CG;
  const int row0 = blockIdx.x * BM;

  // stage A tile (BM x 128) via float4
  for (int i = t; i < BM * 32; i += 256) {
    int r = i >> 5, c4 = i & 31;
    int gr = row0 + r;
    float4 v = make_float4(0.f, 0.f, 0.f, 0.f);
    if (gr < M) v = reinterpret_cast<const float4*>(A)[(size_t)gr * 32 + c4];
    *reinterpret_cast<float4*>(&sA[r][c4 * 4]) = v;
  }
  __syncthreads();

  float acc[4][4] = {};
#pragma unroll 4
  for (int k = 0; k < 128; ++k) {
    float4 w = reinterpret_cast<const float4*>(W + (size_t)k * N)[tx];
    float a0 = sA[ty * 4 + 0][k];
    float a1 = sA[ty * 4 + 1][k];
    float a2 = sA[ty * 4 + 2][k];
    float a3 = sA[ty * 4 + 3][k];
    acc[0][0] = fmaf(a0, w.x, acc[0][0]); acc[0][1] = fmaf(a0, w.y, acc[0][1]);
    acc[0][2] = fmaf(a0, w.z, acc[0][2]); acc[0][3] = fmaf(a0, w.w, acc[0][3]);
    acc[1][0] = fmaf(a1, w.x, acc[1][0]); acc[1][1] = fmaf(a1, w.y, acc[1][1]);
    acc[1][2] = fmaf(a1, w.z, acc[1][2]); acc[1][3] = fmaf(a1, w.w, acc[1][3]);
    acc[2][0] = fmaf(a2, w.x, acc[2][0]); acc[2][1] = fmaf(a2, w.y, acc[2][1]);
    acc[2][2] = fmaf(a2, w.z, acc[2][2]); acc[2][3] = fmaf(a2, w.w, acc[2][3]);
    acc[3][0] = fmaf(a3, w.x, acc[3][0]); acc[3][1] = fmaf(a3, w.y, acc[3][1]);
    acc[3][2] = fmaf(a3, w.z, acc[3][2]); acc[3][3] = fmaf(a3, w.w, acc[3][3]);
  }

#pragma unroll
  for (int r = 0; r < 4; ++r) {
    int gr = row0 + ty * 4 + r;
    if (gr < M) {
      float4 o = make_float4(acc[r][0], acc[r][1], acc[r][2], acc[r][3]);
      reinterpret_cast<float4*>(C + (size_t)gr * N)[tx] = o;
    }
  }
}

// out[i,c] = (sum_{j in CSR[i]} nrm[j]*H[src[j],c]) + dinv[i]^2*H[i,c] + bias[c]
template <int C, bool RELU>
__global__ void agg_kernel(const float* __restrict__ H, const float* __restrict__ bias,
                           const int* __restrict__ offs, const int* __restrict__ src,
                           const float* __restrict__ nrm, const float* __restrict__ dinv,
                           float* __restrict__ out, int n) {
  int i = blockIdx.x;
  int c = threadIdx.x;
  float di = dinv[i];
  float acc = di * di * H[(size_t)i * C + c];
  int j0 = offs[i], j1 = offs[i + 1];
  for (int j = j0; j < j1; ++j) {
    acc = fmaf(nrm[j], H[(size_t)src[j] * C + c], acc);
  }
  acc += bias[c];
  if (RELU) acc = fmaxf(acc, 0.0f);
  out[(size_t)i * C + c] = acc;
}

static inline size_t ws_align(size_t x) { return (x + 255) & ~(size_t)255; }

extern "C" void kernel_launch(void* const* d_in, const int* in_sizes, int n_in,
                              void* d_out, int out_size, void* d_ws, size_t ws_size,
                              hipStream_t stream) {
  const float* x  = (const float*)d_in[0];
  const int*   ei = (const int*)d_in[1];     // int32 per harness integer cast
  const float* ew = (const float*)d_in[2];
  const float* W1 = (const float*)d_in[3];
  const float* b1 = (const float*)d_in[4];
  const float* W2 = (const float*)d_in[5];
  const float* b2 = (const float*)d_in[6];
  float*       out = (float*)d_out;

  const int n = in_sizes[0] / 128;   // 50000
  const int E = in_sizes[2];         // 800000

  char* ws = (char*)d_ws;
  size_t off = 0;
  auto alloc = [&](size_t bytes) -> char* {
    char* p = ws + off;
    off = ws_align(off + bytes);
    return p;
  };
  float* bufA   = (float*)alloc((size_t)n * 128 * sizeof(float)); // softmax out, later h1-agg
  float* bufB   = (float*)alloc((size_t)n * 128 * sizeof(float)); // h1, later h2
  char*  zbase  = ws + off;                                        // contiguous zeroed region
  float* deg_w  = (float*)alloc((size_t)n * sizeof(float));
  int*   counts = (int*)  alloc((size_t)n * sizeof(int));
  int*   cursor = (int*)  alloc((size_t)n * sizeof(int));
  size_t zbytes = (size_t)((ws + off) - zbase);
  float* dinv   = (float*)alloc((size_t)n * sizeof(float));
  int*   offs   = (int*)  alloc((size_t)(n + 1) * sizeof(int));
  int*   csr_s  = (int*)  alloc((size_t)E * sizeof(int));
  float* csr_w  = (float*)alloc((size_t)E * sizeof(float));
  (void)ws_size; (void)n_in; (void)out_size;

  hipMemsetAsync(zbase, 0, zbytes, stream);

  // ---- CSR build (per call; ws is re-poisoned between launches) ----
  deg_kernel<<<(E + 255) / 256, 256, 0, stream>>>(ei, ew, deg_w, counts, E);
  dinv_kernel<<<(n + 255) / 256, 256, 0, stream>>>(deg_w, dinv, n);
  scan_kernel<<<1, 1024, 0, stream>>>(counts, offs, n);
  scatter_kernel<<<(E + 255) / 256, 256, 0, stream>>>(ei, ew, dinv, offs, cursor,
                                                      csr_s, csr_w, E);

  // ---- layer pipeline ----
  softmax_kernel<<<((size_t)n * 64 + 255) / 256, 256, 0, stream>>>(x, bufA, n);
  gemm_kernel<128><<<(n + 31) / 32, 256, 0, stream>>>(bufA, W1, bufB, n);          // h1 = s@W1
  agg_kernel<128, true><<<n, 128, 0, stream>>>(bufB, b1, offs, csr_s, csr_w,
                                               dinv, bufA, n);                     // h1a
  gemm_kernel<64><<<(n + 63) / 64, 256, 0, stream>>>(bufA, W2, bufB, n);           // h2 = h1a@W2
  agg_kernel<64, false><<<n, 64, 0, stream>>>(bufB, b2, offs, csr_s, csr_w,
                                              dinv, out, n);
}

// Round 11
// 456.589 us; speedup vs baseline: 1.0540x; 1.0540x over previous
//
#include <hip/hip_runtime.h>
#include <math.h>

// ---------------------------------------------------------------------------
// 2-layer GCN:  out = GCN2( relu(GCN1( softmax(x) )) )
// out_i = dinv_i * sum_{e: col=i} (dinv[row]*ew) * h[row] + dinv_i^2 * h_i + b
// (dinv[col] factored out of the edge weight -> applied once per node in agg.)
// CSR grouped by destination rebuilt on-device each call.
// R9: wave-per-node agg with float2 lanes + 4x unrolled gathers (4 outstanding
//     512B loads/wave, was 1); dinv fused into scan; scatter drops dinv[col].
// R10/R11: verbatim resubmits (acquisition timeouts; kernel unmeasured).
// ---------------------------------------------------------------------------

__global__ void softmax_kernel(const float* __restrict__ x, float* __restrict__ out,
                               int nrows) {
  int gid  = blockIdx.x * blockDim.x + threadIdx.x;
  int row  = gid >> 6;          // one wave per row, 2 ch/lane
  int lane = gid & 63;
  if (row >= nrows) return;
  const float2* xr = reinterpret_cast<const float2*>(x + (size_t)row * 128);
  float2 v = xr[lane];
  float m = fmaxf(v.x, v.y);
#pragma unroll
  for (int o = 32; o > 0; o >>= 1) m = fmaxf(m, __shfl_xor(m, o));
  float e0 = expf(v.x - m), e1 = expf(v.y - m);
  float s = e0 + e1;
#pragma unroll
  for (int o = 32; o > 0; o >>= 1) s += __shfl_xor(s, o);
  float inv = 1.0f / s;
  float2 r; r.x = e0 * inv; r.y = e1 * inv;
  reinterpret_cast<float2*>(out + (size_t)row * 128)[lane] = r;
}

// deg_w[col] += ew ; counts[col] += 1   (self-loop added later as +1.0)
__global__ void deg_kernel(const int* __restrict__ ei, const float* __restrict__ ew,
                           float* __restrict__ deg_w, int* __restrict__ counts, int E) {
  int e = blockIdx.x * blockDim.x + threadIdx.x;
  if (e >= E) return;
  int c = ei[(size_t)E + e];
  atomicAdd(&deg_w[c], ew[e]);
  atomicAdd(&counts[c], 1);
}

// exclusive scan of counts -> offs, plus dinv computation (independent work)
__global__ void scan_kernel(const int* __restrict__ counts, int* __restrict__ offs,
                            const float* __restrict__ deg_w, float* __restrict__ dinv,
                            int n) {
  int t = threadIdx.x;
  for (int i = t; i < n; i += 1024) {
    float d = deg_w[i] + 1.0f;       // + self loop weight
    dinv[i] = (d > 0.0f) ? (1.0f / sqrtf(d)) : 0.0f;
  }
  __shared__ int sums[1024];
  int chunk = (n + 1023) / 1024;
  int lo = t * chunk;
  int hi = lo + chunk; if (hi > n) hi = n;
  int s = 0;
  for (int i = lo; i < hi; ++i) s += counts[i];
  sums[t] = s;
  __syncthreads();
  for (int d = 1; d < 1024; d <<= 1) {
    int v = (t >= d) ? sums[t - d] : 0;
    __syncthreads();
    sums[t] += v;
    __syncthreads();
  }
  int run = (t == 0) ? 0 : sums[t - 1];
  for (int i = lo; i < hi; ++i) { offs[i] = run; run += counts[i]; }
  if (t == 1023) offs[n] = sums[1023];
}

// csr_w = dinv[row]*ew  (dinv[col] applied in agg epilogue)
__global__ void scatter_kernel(const int* __restrict__ ei, const float* __restrict__ ew,
                               const float* __restrict__ dinv, const int* __restrict__ offs,
                               int* __restrict__ cursor, int* __restrict__ csr_src,
                               float* __restrict__ csr_nrm, int E) {
  int e = blockIdx.x * blockDim.x + threadIdx.x;
  if (e >= E) return;
  int r = ei[e];
  int c = ei[(size_t)E + e];
  int pos = offs[c] + atomicAdd(&cursor[c], 1);
  csr_src[pos] = r;
  csr_nrm[pos] = dinv[r] * ew[e];
}

// C = A(M x 128) @ W(128 x N), fp32, 4x4 register tile per thread, A tile in LDS
template <int N>
__global__ __launch_bounds__(256) void gemm_kernel(const float* __restrict__ A,
                                                   const float* __restrict__ W,
                                                   float* __restrict__ C, int M) {
  constexpr int CG  = N / 4;       // float4 column groups (32 or 16)
  constexpr int RG  = 256 / CG;    // row groups (8 or 16)
  constexpr int BM  = RG * 4;      // rows per block (32 or 64)
  constexpr int LDA = 132;         // padded
  __shared__ float sA[BM][LDA];
  const int t   = threadIdx.x;
  const int tx  = t % CG;
  const int ty  = t / CG;
  const int row0 = blockIdx.x * BM;

  for (int i = t; i < BM * 32; i += 256) {
    int r = i >> 5, c4 = i & 31;
    int gr = row0 + r;
    float4 v = make_float4(0.f, 0.f, 0.f, 0.f);
    if (gr < M) v = reinterpret_cast<const float4*>(A)[(size_t)gr * 32 + c4];
    *reinterpret_cast<float4*>(&sA[r][c4 * 4]) = v;
  }
  __syncthreads();

  float acc[4][4] = {};
#pragma unroll 4
  for (int k = 0; k < 128; ++k) {
    float4 w = reinterpret_cast<const float4*>(W + (size_t)k * N)[tx];
    float a0 = sA[ty * 4 + 0][k];
    float a1 = sA[ty * 4 + 1][k];
    float a2 = sA[ty * 4 + 2][k];
    float a3 = sA[ty * 4 + 3][k];
    acc[0][0] = fmaf(a0, w.x, acc[0][0]); acc[0][1] = fmaf(a0, w.y, acc[0][1]);
    acc[0][2] = fmaf(a0, w.z, acc[0][2]); acc[0][3] = fmaf(a0, w.w, acc[0][3]);
    acc[1][0] = fmaf(a1, w.x, acc[1][0]); acc[1][1] = fmaf(a1, w.y, acc[1][1]);
    acc[1][2] = fmaf(a1, w.z, acc[1][2]); acc[1][3] = fmaf(a1, w.w, acc[1][3]);
    acc[2][0] = fmaf(a2, w.x, acc[2][0]); acc[2][1] = fmaf(a2, w.y, acc[2][1]);
    acc[2][2] = fmaf(a2, w.z, acc[2][2]); acc[2][3] = fmaf(a2, w.w, acc[2][3]);
    acc[3][0] = fmaf(a3, w.x, acc[3][0]); acc[3][1] = fmaf(a3, w.y, acc[3][1]);
    acc[3][2] = fmaf(a3, w.z, acc[3][2]); acc[3][3] = fmaf(a3, w.w, acc[3][3]);
  }

#pragma unroll
  for (int r = 0; r < 4; ++r) {
    int gr = row0 + ty * 4 + r;
    if (gr < M) {
      float4 o = make_float4(acc[r][0], acc[r][1], acc[r][2], acc[r][3]);
      reinterpret_cast<float4*>(C + (size_t)gr * N)[tx] = o;
    }
  }
}

// Wave-per-node aggregation, C=128: lane holds float2; 4-wide unrolled gather.
// out[i] = dinv_i * sum_j w_j*H[src_j] + dinv_i^2*H[i] + bias ; optional relu.
template <bool RELU>
__global__ __launch_bounds__(256) void agg128_kernel(
    const float* __restrict__ H, const float* __restrict__ bias,
    const int* __restrict__ offs, const int* __restrict__ src,
    const float* __restrict__ nrm, const float* __restrict__ dinv,
    float* __restrict__ out, int n) {
  int wave = (blockIdx.x << 2) | (threadIdx.x >> 6);
  int lane = threadIdx.x & 63;
  if (wave >= n) return;
  const int i = wave;
  const float2* H2 = reinterpret_cast<const float2*>(H);
  float2 acc = make_float2(0.f, 0.f);
  int j0 = offs[i], j1 = offs[i + 1];
  int j = j0;
  for (; j + 3 < j1; j += 4) {
    int   s0 = src[j],   s1 = src[j+1], s2 = src[j+2], s3 = src[j+3];
    float w0 = nrm[j],   w1 = nrm[j+1], w2 = nrm[j+2], w3 = nrm[j+3];
    float2 h0 = H2[(size_t)s0 * 64 + lane];
    float2 h1 = H2[(size_t)s1 * 64 + lane];
    float2 h2 = H2[(size_t)s2 * 64 + lane];
    float2 h3 = H2[(size_t)s3 * 64 + lane];
    acc.x = fmaf(w0, h0.x, acc.x); acc.y = fmaf(w0, h0.y, acc.y);
    acc.x = fmaf(w1, h1.x, acc.x); acc.y = fmaf(w1, h1.y, acc.y);
    acc.x = fmaf(w2, h2.x, acc.x); acc.y = fmaf(w2, h2.y, acc.y);
    acc.x = fmaf(w3, h3.x, acc.x); acc.y = fmaf(w3, h3.y, acc.y);
  }
  for (; j < j1; ++j) {
    float w = nrm[j];
    float2 h = H2[(size_t)src[j] * 64 + lane];
    acc.x = fmaf(w, h.x, acc.x); acc.y = fmaf(w, h.y, acc.y);
  }
  float di = dinv[i];
  float2 hs = H2[(size_t)i * 64 + lane];
  float2 b  = reinterpret_cast<const float2*>(bias)[lane];
  float2 o;
  o.x = fmaf(di, acc.x, di * di * hs.x) + b.x;
  o.y = fmaf(di, acc.y, di * di * hs.y) + b.y;
  if (RELU) { o.x = fmaxf(o.x, 0.f); o.y = fmaxf(o.y, 0.f); }
  reinterpret_cast<float2*>(out)[(size_t)i * 64 + lane] = o;
}

// Same, C=64: lane holds one float.
template <bool RELU>
__global__ __launch_bounds__(256) void agg64_kernel(
    const float* __restrict__ H, const float* __restrict__ bias,
    const int* __restrict__ offs, const int* __restrict__ src,
    const float* __restrict__ nrm, const float* __restrict__ dinv,
    float* __restrict__ out, int n) {
  int wave = (blockIdx.x << 2) | (threadIdx.x >> 6);
  int lane = threadIdx.x & 63;
  if (wave >= n) return;
  const int i = wave;
  float acc = 0.f;
  int j0 = offs[i], j1 = offs[i + 1];
  int j = j0;
  for (; j + 3 < j1; j += 4) {
    int   s0 = src[j],   s1 = src[j+1], s2 = src[j+2], s3 = src[j+3];
    float w0 = nrm[j],   w1 = nrm[j+1], w2 = nrm[j+2], w3 = nrm[j+3];
    float h0 = H[(size_t)s0 * 64 + lane];
    float h1 = H[(size_t)s1 * 64 + lane];
    float h2 = H[(size_t)s2 * 64 + lane];
    float h3 = H[(size_t)s3 * 64 + lane];
    acc = fmaf(w0, h0, acc);
    acc = fmaf(w1, h1, acc);
    acc = fmaf(w2, h2, acc);
    acc = fmaf(w3, h3, acc);
  }
  for (; j < j1; ++j) acc = fmaf(nrm[j], H[(size_t)src[j] * 64 + lane], acc);
  float di = dinv[i];
  float hs = H[(size_t)i * 64 + lane];
  float o  = fmaf(di, acc, di * di * hs) + bias[lane];
  if (RELU) o = fmaxf(o, 0.f);
  out[(size_t)i * 64 + lane] = o;
}

static inline size_t ws_align(size_t x) { return (x + 255) & ~(size_t)255; }

extern "C" void kernel_launch(void* const* d_in, const int* in_sizes, int n_in,
                              void* d_out, int out_size, void* d_ws, size_t ws_size,
                              hipStream_t stream) {
  const float* x  = (const float*)d_in[0];
  const int*   ei = (const int*)d_in[1];     // int32 per harness integer cast
  const float* ew = (const float*)d_in[2];
  const float* W1 = (const float*)d_in[3];
  const float* b1 = (const float*)d_in[4];
  const float* W2 = (const float*)d_in[5];
  const float* b2 = (const float*)d_in[6];
  float*       out = (float*)d_out;

  const int n = in_sizes[0] / 128;   // 50000
  const int E = in_sizes[2];         // 800000

  char* ws = (char*)d_ws;
  size_t off = 0;
  auto alloc = [&](size_t bytes) -> char* {
    char* p = ws + off;
    off = ws_align(off + bytes);
    return p;
  };
  float* bufA   = (float*)alloc((size_t)n * 128 * sizeof(float)); // softmax out, later h1-agg
  float* bufB   = (float*)alloc((size_t)n * 128 * sizeof(float)); // h1, later h2
  char*  zbase  = ws + off;                                        // contiguous zeroed region
  float* deg_w  = (float*)alloc((size_t)n * sizeof(float));
  int*   counts = (int*)  alloc((size_t)n * sizeof(int));
  int*   cursor = (int*)  alloc((size_t)n * sizeof(int));
  size_t zbytes = (size_t)((ws + off) - zbase);
  float* dinv   = (float*)alloc((size_t)n * sizeof(float));
  int*   offs   = (int*)  alloc((size_t)(n + 1) * sizeof(int));
  int*   csr_s  = (int*)  alloc((size_t)E * sizeof(int));
  float* csr_w  = (float*)alloc((size_t)E * sizeof(float));
  (void)ws_size; (void)n_in; (void)out_size;

  hipMemsetAsync(zbase, 0, zbytes, stream);

  // ---- CSR build ----
  deg_kernel<<<(E + 255) / 256, 256, 0, stream>>>(ei, ew, deg_w, counts, E);
  scan_kernel<<<1, 1024, 0, stream>>>(counts, offs, deg_w, dinv, n);
  scatter_kernel<<<(E + 255) / 256, 256, 0, stream>>>(ei, ew, dinv, offs, cursor,
                                                      csr_s, csr_w, E);

  // ---- layer pipeline ----
  softmax_kernel<<<((size_t)n * 64 + 255) / 256, 256, 0, stream>>>(x, bufA, n);
  gemm_kernel<128><<<(n + 31) / 32, 256, 0, stream>>>(bufA, W1, bufB, n);       // h1 = s@W1
  agg128_kernel<true><<<(n + 3) / 4, 256, 0, stream>>>(bufB, b1, offs, csr_s,
                                                       csr_w, dinv, bufA, n);   // h1a
  gemm_kernel<64><<<(n + 63) / 64, 256, 0, stream>>>(bufA, W2, bufB, n);        // h2 = h1a@W2
  agg64_kernel<false><<<(n + 3) / 4, 256, 0, stream>>>(bufB, b2, offs, csr_s,
                                                       csr_w, dinv, out, n);
}

// Round 12
// 390.547 us; speedup vs baseline: 1.2322x; 1.1691x over previous
//
#include <hip/hip_runtime.h>
#include <math.h>

// ---------------------------------------------------------------------------
// 2-layer GCN:  out = GCN2( relu(GCN1( softmax(x) )) )
// out_i = dinv_i * sum_{e: col=i} (dinv[row]*ew) * h[row] + dinv_i^2 * h_i + b
// CSR grouped by destination rebuilt on-device each call.
// R9:  wave-per-node agg, 4x unrolled gathers (agg128 91 -> <89 us).
// R12: single-block scan_kernel (89.5 us, 1 CU, latency-serial) replaced by
//      3-kernel multi-block scan (blocksum+dinv / blockscan / blockwrite),
//      each wide-parallel or tiny. Predicted scan path ~10 us.
// ---------------------------------------------------------------------------

__global__ void softmax_kernel(const float* __restrict__ x, float* __restrict__ out,
                               int nrows) {
  int gid  = blockIdx.x * blockDim.x + threadIdx.x;
  int row  = gid >> 6;          // one wave per row, 2 ch/lane
  int lane = gid & 63;
  if (row >= nrows) return;
  const float2* xr = reinterpret_cast<const float2*>(x + (size_t)row * 128);
  float2 v = xr[lane];
  float m = fmaxf(v.x, v.y);
#pragma unroll
  for (int o = 32; o > 0; o >>= 1) m = fmaxf(m, __shfl_xor(m, o));
  float e0 = expf(v.x - m), e1 = expf(v.y - m);
  float s = e0 + e1;
#pragma unroll
  for (int o = 32; o > 0; o >>= 1) s += __shfl_xor(s, o);
  float inv = 1.0f / s;
  float2 r; r.x = e0 * inv; r.y = e1 * inv;
  reinterpret_cast<float2*>(out + (size_t)row * 128)[lane] = r;
}

// deg_w[col] += ew ; counts[col] += 1   (self-loop added later as +1.0)
__global__ void deg_kernel(const int* __restrict__ ei, const float* __restrict__ ew,
                           float* __restrict__ deg_w, int* __restrict__ counts, int E) {
  int e = blockIdx.x * blockDim.x + threadIdx.x;
  if (e >= E) return;
  int c = ei[(size_t)E + e];
  atomicAdd(&deg_w[c], ew[e]);
  atomicAdd(&counts[c], 1);
}

// --- multi-block scan, stage 1: per-block sum of counts; dinv folded in ---
__global__ __launch_bounds__(256) void blocksum_kernel(
    const int* __restrict__ counts, int* __restrict__ blockSum,
    const float* __restrict__ deg_w, float* __restrict__ dinv, int n) {
  int i = blockIdx.x * 256 + threadIdx.x;
  if (i < n) {
    float d = deg_w[i] + 1.0f;       // + self loop weight
    dinv[i] = (d > 0.0f) ? (1.0f / sqrtf(d)) : 0.0f;
  }
  int v = (i < n) ? counts[i] : 0;
  // wave reduce (64 lanes), then cross-wave via LDS
  int s = v;
#pragma unroll
  for (int o = 32; o > 0; o >>= 1) s += __shfl_down(s, o);
  __shared__ int wsum[4];
  int wid = threadIdx.x >> 6, lane = threadIdx.x & 63;
  if (lane == 0) wsum[wid] = s;
  __syncthreads();
  if (threadIdx.x == 0)
    blockSum[blockIdx.x] = wsum[0] + wsum[1] + wsum[2] + wsum[3];
}

// --- stage 2: single-block exclusive scan of blockSum[nb] (nb <= 1024) ---
__global__ __launch_bounds__(1024) void blockscan_kernel(
    int* __restrict__ blockSum, int nb, int* __restrict__ offs, int n) {
  __shared__ int arr[1024];
  int t = threadIdx.x;
  int v = (t < nb) ? blockSum[t] : 0;
  arr[t] = v;
  __syncthreads();
  for (int d = 1; d < 1024; d <<= 1) {
    int u = (t >= d) ? arr[t - d] : 0;
    __syncthreads();
    arr[t] += u;
    __syncthreads();
  }
  if (t < nb) blockSum[t] = arr[t] - v;       // exclusive
  if (t == nb - 1) offs[n] = arr[t];          // grand total
}

// --- stage 3: in-block scan of counts + block offset -> offs[i] ---
__global__ __launch_bounds__(256) void blockwrite_kernel(
    const int* __restrict__ counts, const int* __restrict__ blockSum,
    int* __restrict__ offs, int n) {
  __shared__ int arr[256];
  int t = threadIdx.x;
  int i = blockIdx.x * 256 + t;
  int v = (i < n) ? counts[i] : 0;
  arr[t] = v;
  __syncthreads();
  for (int d = 1; d < 256; d <<= 1) {
    int u = (t >= d) ? arr[t - d] : 0;
    __syncthreads();
    arr[t] += u;
    __syncthreads();
  }
  if (i < n) offs[i] = blockSum[blockIdx.x] + arr[t] - v;  // exclusive
}

// csr_w = dinv[row]*ew  (dinv[col] applied in agg epilogue)
__global__ void scatter_kernel(const int* __restrict__ ei, const float* __restrict__ ew,
                               const float* __restrict__ dinv, const int* __restrict__ offs,
                               int* __restrict__ cursor, int* __restrict__ csr_src,
                               float* __restrict__ csr_nrm, int E) {
  int e = blockIdx.x * blockDim.x + threadIdx.x;
  if (e >= E) return;
  int r = ei[e];
  int c = ei[(size_t)E + e];
  int pos = offs[c] + atomicAdd(&cursor[c], 1);
  csr_src[pos] = r;
  csr_nrm[pos] = dinv[r] * ew[e];
}

// C = A(M x 128) @ W(128 x N), fp32, 4x4 register tile per thread, A tile in LDS
template <int N>
__global__ __launch_bounds__(256) void gemm_kernel(const float* __restrict__ A,
                                                   const float* __restrict__ W,
                                                   float* __restrict__ C, int M) {
  constexpr int CG  = N / 4;       // float4 column groups (32 or 16)
  constexpr int RG  = 256 / CG;    // row groups (8 or 16)
  constexpr int BM  = RG * 4;      // rows per block (32 or 64)
  constexpr int LDA = 132;         // padded
  __shared__ float sA[BM][LDA];
  const int t   = threadIdx.x;
  const int tx  = t % CG;
  const int ty  = t / CG;
  const int row0 = blockIdx.x * BM;

  for (int i = t; i < BM * 32; i += 256) {
    int r = i >> 5, c4 = i & 31;
    int gr = row0 + r;
    float4 v = make_float4(0.f, 0.f, 0.f, 0.f);
    if (gr < M) v = reinterpret_cast<const float4*>(A)[(size_t)gr * 32 + c4];
    *reinterpret_cast<float4*>(&sA[r][c4 * 4]) = v;
  }
  __syncthreads();

  float acc[4][4] = {};
#pragma unroll 4
  for (int k = 0; k < 128; ++k) {
    float4 w = reinterpret_cast<const float4*>(W + (size_t)k * N)[tx];
    float a0 = sA[ty * 4 + 0][k];
    float a1 = sA[ty * 4 + 1][k];
    float a2 = sA[ty * 4 + 2][k];
    float a3 = sA[ty * 4 + 3][k];
    acc[0][0] = fmaf(a0, w.x, acc[0][0]); acc[0][1] = fmaf(a0, w.y, acc[0][1]);
    acc[0][2] = fmaf(a0, w.z, acc[0][2]); acc[0][3] = fmaf(a0, w.w, acc[0][3]);
    acc[1][0] = fmaf(a1, w.x, acc[1][0]); acc[1][1] = fmaf(a1, w.y, acc[1][1]);
    acc[1][2] = fmaf(a1, w.z, acc[1][2]); acc[1][3] = fmaf(a1, w.w, acc[1][3]);
    acc[2][0] = fmaf(a2, w.x, acc[2][0]); acc[2][1] = fmaf(a2, w.y, acc[2][1]);
    acc[2][2] = fmaf(a2, w.z, acc[2][2]); acc[2][3] = fmaf(a2, w.w, acc[2][3]);
    acc[3][0] = fmaf(a3, w.x, acc[3][0]); acc[3][1] = fmaf(a3, w.y, acc[3][1]);
    acc[3][2] = fmaf(a3, w.z, acc[3][2]); acc[3][3] = fmaf(a3, w.w, acc[3][3]);
  }

#pragma unroll
  for (int r = 0; r < 4; ++r) {
    int gr = row0 + ty * 4 + r;
    if (gr < M) {
      float4 o = make_float4(acc[r][0], acc[r][1], acc[r][2], acc[r][3]);
      reinterpret_cast<float4*>(C + (size_t)gr * N)[tx] = o;
    }
  }
}

// Wave-per-node aggregation, C=128: lane holds float2; 4-wide unrolled gather.
template <bool RELU>
__global__ __launch_bounds__(256) void agg128_kernel(
    const float* __restrict__ H, const float* __restrict__ bias,
    const int* __restrict__ offs, const int* __restrict__ src,
    const float* __restrict__ nrm, const float* __restrict__ dinv,
    float* __restrict__ out, int n) {
  int wave = (blockIdx.x << 2) | (threadIdx.x >> 6);
  int lane = threadIdx.x & 63;
  if (wave >= n) return;
  const int i = wave;
  const float2* H2 = reinterpret_cast<const float2*>(H);
  float2 acc = make_float2(0.f, 0.f);
  int j0 = offs[i], j1 = offs[i + 1];
  int j = j0;
  for (; j + 3 < j1; j += 4) {
    int   s0 = src[j],   s1 = src[j+1], s2 = src[j+2], s3 = src[j+3];
    float w0 = nrm[j],   w1 = nrm[j+1], w2 = nrm[j+2], w3 = nrm[j+3];
    float2 h0 = H2[(size_t)s0 * 64 + lane];
    float2 h1 = H2[(size_t)s1 * 64 + lane];
    float2 h2 = H2[(size_t)s2 * 64 + lane];
    float2 h3 = H2[(size_t)s3 * 64 + lane];
    acc.x = fmaf(w0, h0.x, acc.x); acc.y = fmaf(w0, h0.y, acc.y);
    acc.x = fmaf(w1, h1.x, acc.x); acc.y = fmaf(w1, h1.y, acc.y);
    acc.x = fmaf(w2, h2.x, acc.x); acc.y = fmaf(w2, h2.y, acc.y);
    acc.x = fmaf(w3, h3.x, acc.x); acc.y = fmaf(w3, h3.y, acc.y);
  }
  for (; j < j1; ++j) {
    float w = nrm[j];
    float2 h = H2[(size_t)src[j] * 64 + lane];
    acc.x = fmaf(w, h.x, acc.x); acc.y = fmaf(w, h.y, acc.y);
  }
  float di = dinv[i];
  float2 hs = H2[(size_t)i * 64 + lane];
  float2 b  = reinterpret_cast<const float2*>(bias)[lane];
  float2 o;
  o.x = fmaf(di, acc.x, di * di * hs.x) + b.x;
  o.y = fmaf(di, acc.y, di * di * hs.y) + b.y;
  if (RELU) { o.x = fmaxf(o.x, 0.f); o.y = fmaxf(o.y, 0.f); }
  reinterpret_cast<float2*>(out)[(size_t)i * 64 + lane] = o;
}

// Same, C=64: lane holds one float.
template <bool RELU>
__global__ __launch_bounds__(256) void agg64_kernel(
    const float* __restrict__ H, const float* __restrict__ bias,
    const int* __restrict__ offs, const int* __restrict__ src,
    const float* __restrict__ nrm, const float* __restrict__ dinv,
    float* __restrict__ out, int n) {
  int wave = (blockIdx.x << 2) | (threadIdx.x >> 6);
  int lane = threadIdx.x & 63;
  if (wave >= n) return;
  const int i = wave;
  float acc = 0.f;
  int j0 = offs[i], j1 = offs[i + 1];
  int j = j0;
  for (; j + 3 < j1; j += 4) {
    int   s0 = src[j],   s1 = src[j+1], s2 = src[j+2], s3 = src[j+3];
    float w0 = nrm[j],   w1 = nrm[j+1], w2 = nrm[j+2], w3 = nrm[j+3];
    float h0 = H[(size_t)s0 * 64 + lane];
    float h1 = H[(size_t)s1 * 64 + lane];
    float h2 = H[(size_t)s2 * 64 + lane];
    float h3 = H[(size_t)s3 * 64 + lane];
    acc = fmaf(w0, h0, acc);
    acc = fmaf(w1, h1, acc);
    acc = fmaf(w2, h2, acc);
    acc = fmaf(w3, h3, acc);
  }
  for (; j < j1; ++j) acc = fmaf(nrm[j], H[(size_t)src[j] * 64 + lane], acc);
  float di = dinv[i];
  float hs = H[(size_t)i * 64 + lane];
  float o  = fmaf(di, acc, di * di * hs) + bias[lane];
  if (RELU) o = fmaxf(o, 0.f);
  out[(size_t)i * 64 + lane] = o;
}

static inline size_t ws_align(size_t x) { return (x + 255) & ~(size_t)255; }

extern "C" void kernel_launch(void* const* d_in, const int* in_sizes, int n_in,
                              void* d_out, int out_size, void* d_ws, size_t ws_size,
                              hipStream_t stream) {
  const float* x  = (const float*)d_in[0];
  const int*   ei = (const int*)d_in[1];     // int32 per harness integer cast
  const float* ew = (const float*)d_in[2];
  const float* W1 = (const float*)d_in[3];
  const float* b1 = (const float*)d_in[4];
  const float* W2 = (const float*)d_in[5];
  const float* b2 = (const float*)d_in[6];
  float*       out = (float*)d_out;

  const int n = in_sizes[0] / 128;   // 50000
  const int E = in_sizes[2];         // 800000
  const int nb = (n + 255) / 256;    // scan blocks (196; must be <= 1024)

  char* ws = (char*)d_ws;
  size_t off = 0;
  auto alloc = [&](size_t bytes) -> char* {
    char* p = ws + off;
    off = ws_align(off + bytes);
    return p;
  };
  float* bufA   = (float*)alloc((size_t)n * 128 * sizeof(float)); // softmax out, later h1-agg
  float* bufB   = (float*)alloc((size_t)n * 128 * sizeof(float)); // h1, later h2
  char*  zbase  = ws + off;                                        // contiguous zeroed region
  float* deg_w  = (float*)alloc((size_t)n * sizeof(float));
  int*   counts = (int*)  alloc((size_t)n * sizeof(int));
  int*   cursor = (int*)  alloc((size_t)n * sizeof(int));
  size_t zbytes = (size_t)((ws + off) - zbase);
  float* dinv   = (float*)alloc((size_t)n * sizeof(float));
  int*   offs   = (int*)  alloc((size_t)(n + 1) * sizeof(int));
  int*   bsum   = (int*)  alloc((size_t)1024 * sizeof(int));
  int*   csr_s  = (int*)  alloc((size_t)E * sizeof(int));
  float* csr_w  = (float*)alloc((size_t)E * sizeof(float));
  (void)ws_size; (void)n_in; (void)out_size;

  hipMemsetAsync(zbase, 0, zbytes, stream);

  // ---- CSR build ----
  deg_kernel<<<(E + 255) / 256, 256, 0, stream>>>(ei, ew, deg_w, counts, E);
  blocksum_kernel<<<nb, 256, 0, stream>>>(counts, bsum, deg_w, dinv, n);
  blockscan_kernel<<<1, 1024, 0, stream>>>(bsum, nb, offs, n);
  blockwrite_kernel<<<nb, 256, 0, stream>>>(counts, bsum, offs, n);
  scatter_kernel<<<(E + 255) / 256, 256, 0, stream>>>(ei, ew, dinv, offs, cursor,
                                                      csr_s, csr_w, E);

  // ---- layer pipeline ----
  softmax_kernel<<<((size_t)n * 64 + 255) / 256, 256, 0, stream>>>(x, bufA, n);
  gemm_kernel<128><<<(n + 31) / 32, 256, 0, stream>>>(bufA, W1, bufB, n);       // h1 = s@W1
  agg128_kernel<true><<<(n + 3) / 4, 256, 0, stream>>>(bufB, b1, offs, csr_s,
                                                       csr_w, dinv, bufA, n);   // h1a
  gemm_kernel<64><<<(n + 63) / 64, 256, 0, stream>>>(bufA, W2, bufB, n);        // h2 = h1a@W2
  agg64_kernel<false><<<(n + 3) / 4, 256, 0, stream>>>(bufB, b2, offs, csr_s,
                                                       csr_w, dinv, out, n);
}

// Round 13
// 365.821 us; speedup vs baseline: 1.3155x; 1.0676x over previous
//
#include <hip/hip_runtime.h>
#include <math.h>

// ---------------------------------------------------------------------------
// 2-layer GCN:  out = GCN2( relu(GCN1( softmax(x) )) )
// out_i = dinv_i * sum_{e: col=i} (dinv[row]*ew) * h[row] + dinv_i^2 * h_i + b
// CSR grouped by destination rebuilt on-device each call.
// R9:  wave-per-node agg, 4x unrolled gathers.
// R12: multi-block scan (89.5 -> ~10 us scan path).
// R13: deg_kernel (76.5 us, 2 atomics/edge, memory-side RMW-bound) split:
//      count (1 atomic/edge) + degseg (atomic-free segment sum from CSR) +
//      scale (csr_w *= dinv[src]). deg_w buffer eliminated.
// ---------------------------------------------------------------------------

__global__ void softmax_kernel(const float* __restrict__ x, float* __restrict__ out,
                               int nrows) {
  int gid  = blockIdx.x * blockDim.x + threadIdx.x;
  int row  = gid >> 6;          // one wave per row, 2 ch/lane
  int lane = gid & 63;
  if (row >= nrows) return;
  const float2* xr = reinterpret_cast<const float2*>(x + (size_t)row * 128);
  float2 v = xr[lane];
  float m = fmaxf(v.x, v.y);
#pragma unroll
  for (int o = 32; o > 0; o >>= 1) m = fmaxf(m, __shfl_xor(m, o));
  float e0 = expf(v.x - m), e1 = expf(v.y - m);
  float s = e0 + e1;
#pragma unroll
  for (int o = 32; o > 0; o >>= 1) s += __shfl_xor(s, o);
  float inv = 1.0f / s;
  float2 r; r.x = e0 * inv; r.y = e1 * inv;
  reinterpret_cast<float2*>(out + (size_t)row * 128)[lane] = r;
}

// counts[col] += 1  (single atomic per edge)
__global__ void count_kernel(const int* __restrict__ ei, int* __restrict__ counts, int E) {
  int e = blockIdx.x * blockDim.x + threadIdx.x;
  if (e >= E) return;
  atomicAdd(&counts[ei[(size_t)E + e]], 1);
}

// --- multi-block scan, stage 1: per-block sum of counts ---
__global__ __launch_bounds__(256) void blocksum_kernel(
    const int* __restrict__ counts, int* __restrict__ blockSum, int n) {
  int i = blockIdx.x * 256 + threadIdx.x;
  int v = (i < n) ? counts[i] : 0;
  int s = v;
#pragma unroll
  for (int o = 32; o > 0; o >>= 1) s += __shfl_down(s, o);
  __shared__ int wsum[4];
  int wid = threadIdx.x >> 6, lane = threadIdx.x & 63;
  if (lane == 0) wsum[wid] = s;
  __syncthreads();
  if (threadIdx.x == 0)
    blockSum[blockIdx.x] = wsum[0] + wsum[1] + wsum[2] + wsum[3];
}

// --- stage 2: single-block exclusive scan of blockSum[nb] (nb <= 1024) ---
__global__ __launch_bounds__(1024) void blockscan_kernel(
    int* __restrict__ blockSum, int nb, int* __restrict__ offs, int n) {
  __shared__ int arr[1024];
  int t = threadIdx.x;
  int v = (t < nb) ? blockSum[t] : 0;
  arr[t] = v;
  __syncthreads();
  for (int d = 1; d < 1024; d <<= 1) {
    int u = (t >= d) ? arr[t - d] : 0;
    __syncthreads();
    arr[t] += u;
    __syncthreads();
  }
  if (t < nb) blockSum[t] = arr[t] - v;       // exclusive
  if (t == nb - 1) offs[n] = arr[t];          // grand total
}

// --- stage 3: in-block scan of counts + block offset -> offs[i] ---
__global__ __launch_bounds__(256) void blockwrite_kernel(
    const int* __restrict__ counts, const int* __restrict__ blockSum,
    int* __restrict__ offs, int n) {
  __shared__ int arr[256];
  int t = threadIdx.x;
  int i = blockIdx.x * 256 + t;
  int v = (i < n) ? counts[i] : 0;
  arr[t] = v;
  __syncthreads();
  for (int d = 1; d < 256; d <<= 1) {
    int u = (t >= d) ? arr[t - d] : 0;
    __syncthreads();
    arr[t] += u;
    __syncthreads();
  }
  if (i < n) offs[i] = blockSum[blockIdx.x] + arr[t] - v;  // exclusive
}

// csr_s[pos]=row, csr_w[pos]=ew  (raw; dinv applied by scale_kernel)
__global__ void scatter_kernel(const int* __restrict__ ei, const float* __restrict__ ew,
                               const int* __restrict__ offs, int* __restrict__ cursor,
                               int* __restrict__ csr_src, float* __restrict__ csr_nrm,
                               int E) {
  int e = blockIdx.x * blockDim.x + threadIdx.x;
  if (e >= E) return;
  int r = ei[e];
  int c = ei[(size_t)E + e];
  int pos = offs[c] + atomicAdd(&cursor[c], 1);
  csr_src[pos] = r;
  csr_nrm[pos] = ew[e];
}

// deg_i = 1 + sum of csr_w over node i's segment (atomic-free); dinv = rsqrt
__global__ void degseg_kernel(const int* __restrict__ offs,
                              const float* __restrict__ csr_w,
                              float* __restrict__ dinv, int n) {
  int i = blockIdx.x * blockDim.x + threadIdx.x;
  if (i >= n) return;
  int j0 = offs[i], j1 = offs[i + 1];
  float d = 1.0f;                  // self loop weight
  for (int j = j0; j < j1; ++j) d += csr_w[j];
  dinv[i] = (d > 0.0f) ? (1.0f / sqrtf(d)) : 0.0f;
}

// csr_w[j] *= dinv[src[j]]
__global__ void scale_kernel(const int* __restrict__ csr_s, float* __restrict__ csr_w,
                             const float* __restrict__ dinv, int E) {
  int j = blockIdx.x * blockDim.x + threadIdx.x;
  if (j >= E) return;
  csr_w[j] *= dinv[csr_s[j]];
}

// C = A(M x 128) @ W(128 x N), fp32, 4x4 register tile per thread, A tile in LDS
template <int N>
__global__ __launch_bounds__(256) void gemm_kernel(const float* __restrict__ A,
                                                   const float* __restrict__ W,
                                                   float* __restrict__ C, int M) {
  constexpr int CG  = N / 4;       // float4 column groups (32 or 16)
  constexpr int RG  = 256 / CG;    // row groups (8 or 16)
  constexpr int BM  = RG * 4;      // rows per block (32 or 64)
  constexpr int LDA = 132;         // padded
  __shared__ float sA[BM][LDA];
  const int t   = threadIdx.x;
  const int tx  = t % CG;
  const int ty  = t / CG;
  const int row0 = blockIdx.x * BM;

  for (int i = t; i < BM * 32; i += 256) {
    int r = i >> 5, c4 = i & 31;
    int gr = row0 + r;
    float4 v = make_float4(0.f, 0.f, 0.f, 0.f);
    if (gr < M) v = reinterpret_cast<const float4*>(A)[(size_t)gr * 32 + c4];
    *reinterpret_cast<float4*>(&sA[r][c4 * 4]) = v;
  }
  __syncthreads();

  float acc[4][4] = {};
#pragma unroll 4
  for (int k = 0; k < 128; ++k) {
    float4 w = reinterpret_cast<const float4*>(W + (size_t)k * N)[tx];
    float a0 = sA[ty * 4 + 0][k];
    float a1 = sA[ty * 4 + 1][k];
    float a2 = sA[ty * 4 + 2][k];
    float a3 = sA[ty * 4 + 3][k];
    acc[0][0] = fmaf(a0, w.x, acc[0][0]); acc[0][1] = fmaf(a0, w.y, acc[0][1]);
    acc[0][2] = fmaf(a0, w.z, acc[0][2]); acc[0][3] = fmaf(a0, w.w, acc[0][3]);
    acc[1][0] = fmaf(a1, w.x, acc[1][0]); acc[1][1] = fmaf(a1, w.y, acc[1][1]);
    acc[1][2] = fmaf(a1, w.z, acc[1][2]); acc[1][3] = fmaf(a1, w.w, acc[1][3]);
    acc[2][0] = fmaf(a2, w.x, acc[2][0]); acc[2][1] = fmaf(a2, w.y, acc[2][1]);
    acc[2][2] = fmaf(a2, w.z, acc[2][2]); acc[2][3] = fmaf(a2, w.w, acc[2][3]);
    acc[3][0] = fmaf(a3, w.x, acc[3][0]); acc[3][1] = fmaf(a3, w.y, acc[3][1]);
    acc[3][2] = fmaf(a3, w.z, acc[3][2]); acc[3][3] = fmaf(a3, w.w, acc[3][3]);
  }

#pragma unroll
  for (int r = 0; r < 4; ++r) {
    int gr = row0 + ty * 4 + r;
    if (gr < M) {
      float4 o = make_float4(acc[r][0], acc[r][1], acc[r][2], acc[r][3]);
      reinterpret_cast<float4*>(C + (size_t)gr * N)[tx] = o;
    }
  }
}

// Wave-per-node aggregation, C=128: lane holds float2; 4-wide unrolled gather.
template <bool RELU>
__global__ __launch_bounds__(256) void agg128_kernel(
    const float* __restrict__ H, const float* __restrict__ bias,
    const int* __restrict__ offs, const int* __restrict__ src,
    const float* __restrict__ nrm, const float* __restrict__ dinv,
    float* __restrict__ out, int n) {
  int wave = (blockIdx.x << 2) | (threadIdx.x >> 6);
  int lane = threadIdx.x & 63;
  if (wave >= n) return;
  const int i = wave;
  const float2* H2 = reinterpret_cast<const float2*>(H);
  float2 acc = make_float2(0.f, 0.f);
  int j0 = offs[i], j1 = offs[i + 1];
  int j = j0;
  for (; j + 3 < j1; j += 4) {
    int   s0 = src[j],   s1 = src[j+1], s2 = src[j+2], s3 = src[j+3];
    float w0 = nrm[j],   w1 = nrm[j+1], w2 = nrm[j+2], w3 = nrm[j+3];
    float2 h0 = H2[(size_t)s0 * 64 + lane];
    float2 h1 = H2[(size_t)s1 * 64 + lane];
    float2 h2 = H2[(size_t)s2 * 64 + lane];
    float2 h3 = H2[(size_t)s3 * 64 + lane];
    acc.x = fmaf(w0, h0.x, acc.x); acc.y = fmaf(w0, h0.y, acc.y);
    acc.x = fmaf(w1, h1.x, acc.x); acc.y = fmaf(w1, h1.y, acc.y);
    acc.x = fmaf(w2, h2.x, acc.x); acc.y = fmaf(w2, h2.y, acc.y);
    acc.x = fmaf(w3, h3.x, acc.x); acc.y = fmaf(w3, h3.y, acc.y);
  }
  for (; j < j1; ++j) {
    float w = nrm[j];
    float2 h = H2[(size_t)src[j] * 64 + lane];
    acc.x = fmaf(w, h.x, acc.x); acc.y = fmaf(w, h.y, acc.y);
  }
  float di = dinv[i];
  float2 hs = H2[(size_t)i * 64 + lane];
  float2 b  = reinterpret_cast<const float2*>(bias)[lane];
  float2 o;
  o.x = fmaf(di, acc.x, di * di * hs.x) + b.x;
  o.y = fmaf(di, acc.y, di * di * hs.y) + b.y;
  if (RELU) { o.x = fmaxf(o.x, 0.f); o.y = fmaxf(o.y, 0.f); }
  reinterpret_cast<float2*>(out)[(size_t)i * 64 + lane] = o;
}

// Same, C=64: lane holds one float.
template <bool RELU>
__global__ __launch_bounds__(256) void agg64_kernel(
    const float* __restrict__ H, const float* __restrict__ bias,
    const int* __restrict__ offs, const int* __restrict__ src,
    const float* __restrict__ nrm, const float* __restrict__ dinv,
    float* __restrict__ out, int n) {
  int wave = (blockIdx.x << 2) | (threadIdx.x >> 6);
  int lane = threadIdx.x & 63;
  if (wave >= n) return;
  const int i = wave;
  float acc = 0.f;
  int j0 = offs[i], j1 = offs[i + 1];
  int j = j0;
  for (; j + 3 < j1; j += 4) {
    int   s0 = src[j],   s1 = src[j+1], s2 = src[j+2], s3 = src[j+3];
    float w0 = nrm[j],   w1 = nrm[j+1], w2 = nrm[j+2], w3 = nrm[j+3];
    float h0 = H[(size_t)s0 * 64 + lane];
    float h1 = H[(size_t)s1 * 64 + lane];
    float h2 = H[(size_t)s2 * 64 + lane];
    float h3 = H[(size_t)s3 * 64 + lane];
    acc = fmaf(w0, h0, acc);
    acc = fmaf(w1, h1, acc);
    acc = fmaf(w2, h2, acc);
    acc = fmaf(w3, h3, acc);
  }
  for (; j < j1; ++j) acc = fmaf(nrm[j], H[(size_t)src[j] * 64 + lane], acc);
  float di = dinv[i];
  float hs = H[(size_t)i * 64 + lane];
  float o  = fmaf(di, acc, di * di * hs) + bias[lane];
  if (RELU) o = fmaxf(o, 0.f);
  out[(size_t)i * 64 + lane] = o;
}

static inline size_t ws_align(size_t x) { return (x + 255) & ~(size_t)255; }

extern "C" void kernel_launch(void* const* d_in, const int* in_sizes, int n_in,
                              void* d_out, int out_size, void* d_ws, size_t ws_size,
                              hipStream_t stream) {
  const float* x  = (const float*)d_in[0];
  const int*   ei = (const int*)d_in[1];     // int32 per harness integer cast
  const float* ew = (const float*)d_in[2];
  const float* W1 = (const float*)d_in[3];
  const float* b1 = (const float*)d_in[4];
  const float* W2 = (const float*)d_in[5];
  const float* b2 = (const float*)d_in[6];
  float*       out = (float*)d_out;

  const int n = in_sizes[0] / 128;   // 50000
  const int E = in_sizes[2];         // 800000
  const int nb = (n + 255) / 256;    // scan blocks (196; must be <= 1024)

  char* ws = (char*)d_ws;
  size_t off = 0;
  auto alloc = [&](size_t bytes) -> char* {
    char* p = ws + off;
    off = ws_align(off + bytes);
    return p;
  };
  float* bufA   = (float*)alloc((size_t)n * 128 * sizeof(float)); // softmax out, later h1-agg
  float* bufB   = (float*)alloc((size_t)n * 128 * sizeof(float)); // h1, later h2
  char*  zbase  = ws + off;                                        // contiguous zeroed region
  int*   counts = (int*)  alloc((size_t)n * sizeof(int));
  int*   cursor = (int*)  alloc((size_t)n * sizeof(int));
  size_t zbytes = (size_t)((ws + off) - zbase);
  float* dinv   = (float*)alloc((size_t)n * sizeof(float));
  int*   offs   = (int*)  alloc((size_t)(n + 1) * sizeof(int));
  int*   bsum   = (int*)  alloc((size_t)1024 * sizeof(int));
  int*   csr_s  = (int*)  alloc((size_t)E * sizeof(int));
  float* csr_w  = (float*)alloc((size_t)E * sizeof(float));
  (void)ws_size; (void)n_in; (void)out_size;

  hipMemsetAsync(zbase, 0, zbytes, stream);

  // ---- CSR build ----
  count_kernel<<<(E + 255) / 256, 256, 0, stream>>>(ei, counts, E);
  blocksum_kernel<<<nb, 256, 0, stream>>>(counts, bsum, n);
  blockscan_kernel<<<1, 1024, 0, stream>>>(bsum, nb, offs, n);
  blockwrite_kernel<<<nb, 256, 0, stream>>>(counts, bsum, offs, n);
  scatter_kernel<<<(E + 255) / 256, 256, 0, stream>>>(ei, ew, offs, cursor,
                                                      csr_s, csr_w, E);
  degseg_kernel<<<(n + 255) / 256, 256, 0, stream>>>(offs, csr_w, dinv, n);
  scale_kernel<<<(E + 255) / 256, 256, 0, stream>>>(csr_s, csr_w, dinv, E);

  // ---- layer pipeline ----
  softmax_kernel<<<((size_t)n * 64 + 255) / 256, 256, 0, stream>>>(x, bufA, n);
  gemm_kernel<128><<<(n + 31) / 32, 256, 0, stream>>>(bufA, W1, bufB, n);       // h1 = s@W1
  agg128_kernel<true><<<(n + 3) / 4, 256, 0, stream>>>(bufB, b1, offs, csr_s,
                                                       csr_w, dinv, bufA, n);   // h1a
  gemm_kernel<64><<<(n + 63) / 64, 256, 0, stream>>>(bufA, W2, bufB, n);        // h2 = h1a@W2
  agg64_kernel<false><<<(n + 3) / 4, 256, 0, stream>>>(bufB, b2, offs, csr_s,
                                                       csr_w, dinv, out, n);
}

// Round 14
// 322.888 us; speedup vs baseline: 1.4904x; 1.1330x over previous
//
#include <hip/hip_runtime.h>
#include <math.h>

// ---------------------------------------------------------------------------
// 2-layer GCN:  out = GCN2( relu(GCN1( softmax(x) )) )
// out_i = dinv_i * sum_{e: col=i} (dinv[row]*ew) * h[row] + dinv_i^2 * h_i + b
// CSR grouped by destination rebuilt on-device each call.
// R9:  wave-per-node agg, 4x unrolled gathers.
// R12: multi-block scan. R13: deg split (count/degseg/scale), 1 atomic/edge.
// R14: scatter de-atomized: count_kernel stores its atomic's return as the
//      per-edge slot; scatter writes ONE packed int2 (src,w) at offs[c]+slot
//      (was: cursor atomic + two 4B random writes -> 82MB WRITE_SIZE).
// ---------------------------------------------------------------------------

__global__ void softmax_kernel(const float* __restrict__ x, float* __restrict__ out,
                               int nrows) {
  int gid  = blockIdx.x * blockDim.x + threadIdx.x;
  int row  = gid >> 6;          // one wave per row, 2 ch/lane
  int lane = gid & 63;
  if (row >= nrows) return;
  const float2* xr = reinterpret_cast<const float2*>(x + (size_t)row * 128);
  float2 v = xr[lane];
  float m = fmaxf(v.x, v.y);
#pragma unroll
  for (int o = 32; o > 0; o >>= 1) m = fmaxf(m, __shfl_xor(m, o));
  float e0 = expf(v.x - m), e1 = expf(v.y - m);
  float s = e0 + e1;
#pragma unroll
  for (int o = 32; o > 0; o >>= 1) s += __shfl_xor(s, o);
  float inv = 1.0f / s;
  float2 r; r.x = e0 * inv; r.y = e1 * inv;
  reinterpret_cast<float2*>(out + (size_t)row * 128)[lane] = r;
}

// counts[col]++ ; slot[e] = old value (unique rank within destination)
__global__ void count_kernel(const int* __restrict__ ei, int* __restrict__ counts,
                             int* __restrict__ slot, int E) {
  int e = blockIdx.x * blockDim.x + threadIdx.x;
  if (e >= E) return;
  slot[e] = atomicAdd(&counts[ei[(size_t)E + e]], 1);
}

// --- multi-block scan, stage 1: per-block sum of counts ---
__global__ __launch_bounds__(256) void blocksum_kernel(
    const int* __restrict__ counts, int* __restrict__ blockSum, int n) {
  int i = blockIdx.x * 256 + threadIdx.x;
  int v = (i < n) ? counts[i] : 0;
  int s = v;
#pragma unroll
  for (int o = 32; o > 0; o >>= 1) s += __shfl_down(s, o);
  __shared__ int wsum[4];
  int wid = threadIdx.x >> 6, lane = threadIdx.x & 63;
  if (lane == 0) wsum[wid] = s;
  __syncthreads();
  if (threadIdx.x == 0)
    blockSum[blockIdx.x] = wsum[0] + wsum[1] + wsum[2] + wsum[3];
}

// --- stage 2: single-block exclusive scan of blockSum[nb] (nb <= 1024) ---
__global__ __launch_bounds__(1024) void blockscan_kernel(
    int* __restrict__ blockSum, int nb, int* __restrict__ offs, int n) {
  __shared__ int arr[1024];
  int t = threadIdx.x;
  int v = (t < nb) ? blockSum[t] : 0;
  arr[t] = v;
  __syncthreads();
  for (int d = 1; d < 1024; d <<= 1) {
    int u = (t >= d) ? arr[t - d] : 0;
    __syncthreads();
    arr[t] += u;
    __syncthreads();
  }
  if (t < nb) blockSum[t] = arr[t] - v;       // exclusive
  if (t == nb - 1) offs[n] = arr[t];          // grand total
}

// --- stage 3: in-block scan of counts + block offset -> offs[i] ---
__global__ __launch_bounds__(256) void blockwrite_kernel(
    const int* __restrict__ counts, const int* __restrict__ blockSum,
    int* __restrict__ offs, int n) {
  __shared__ int arr[256];
  int t = threadIdx.x;
  int i = blockIdx.x * 256 + t;
  int v = (i < n) ? counts[i] : 0;
  arr[t] = v;
  __syncthreads();
  for (int d = 1; d < 256; d <<= 1) {
    int u = (t >= d) ? arr[t - d] : 0;
    __syncthreads();
    arr[t] += u;
    __syncthreads();
  }
  if (i < n) offs[i] = blockSum[blockIdx.x] + arr[t] - v;  // exclusive
}

// pairs[offs[col]+slot[e]] = (row, ew)   -- NO atomics, one 8B random write
__global__ void scatter_kernel(const int* __restrict__ ei, const float* __restrict__ ew,
                               const int* __restrict__ offs, const int* __restrict__ slot,
                               int2* __restrict__ pairs, int E) {
  int e = blockIdx.x * blockDim.x + threadIdx.x;
  if (e >= E) return;
  int r = ei[e];
  int c = ei[(size_t)E + e];
  int pos = offs[c] + slot[e];
  pairs[pos] = make_int2(r, __float_as_int(ew[e]));
}

// deg_i = 1 + sum of pair.w over node i's segment (atomic-free); dinv = rsqrt
__global__ void degseg_kernel(const int* __restrict__ offs,
                              const int2* __restrict__ pairs,
                              float* __restrict__ dinv, int n) {
  int i = blockIdx.x * blockDim.x + threadIdx.x;
  if (i >= n) return;
  int j0 = offs[i], j1 = offs[i + 1];
  float d = 1.0f;                  // self loop weight
  for (int j = j0; j < j1; ++j) d += __int_as_float(pairs[j].y);
  dinv[i] = (d > 0.0f) ? (1.0f / sqrtf(d)) : 0.0f;
}

// pair.w *= dinv[pair.src]   (coalesced 8B RW + L2-resident dinv gather)
__global__ void scale_kernel(int2* __restrict__ pairs,
                             const float* __restrict__ dinv, int E) {
  int j = blockIdx.x * blockDim.x + threadIdx.x;
  if (j >= E) return;
  int2 p = pairs[j];
  p.y = __float_as_int(__int_as_float(p.y) * dinv[p.x]);
  pairs[j] = p;
}

// C = A(M x 128) @ W(128 x N), fp32, 4x4 register tile per thread, A tile in LDS
template <int N>
__global__ __launch_bounds__(256) void gemm_kernel(const float* __restrict__ A,
                                                   const float* __restrict__ W,
                                                   float* __restrict__ C, int M) {
  constexpr int CG  = N / 4;       // float4 column groups (32 or 16)
  constexpr int RG  = 256 / CG;    // row groups (8 or 16)
  constexpr int BM  = RG * 4;      // rows per block (32 or 64)
  constexpr int LDA = 132;         // padded
  __shared__ float sA[BM][LDA];
  const int t   = threadIdx.x;
  const int tx  = t % CG;
  const int ty  = t / CG;
  const int row0 = blockIdx.x * BM;

  for (int i = t; i < BM * 32; i += 256) {
    int r = i >> 5, c4 = i & 31;
    int gr = row0 + r;
    float4 v = make_float4(0.f, 0.f, 0.f, 0.f);
    if (gr < M) v = reinterpret_cast<const float4*>(A)[(size_t)gr * 32 + c4];
    *reinterpret_cast<float4*>(&sA[r][c4 * 4]) = v;
  }
  __syncthreads();

  float acc[4][4] = {};
#pragma unroll 4
  for (int k = 0; k < 128; ++k) {
    float4 w = reinterpret_cast<const float4*>(W + (size_t)k * N)[tx];
    float a0 = sA[ty * 4 + 0][k];
    float a1 = sA[ty * 4 + 1][k];
    float a2 = sA[ty * 4 + 2][k];
    float a3 = sA[ty * 4 + 3][k];
    acc[0][0] = fmaf(a0, w.x, acc[0][0]); acc[0][1] = fmaf(a0, w.y, acc[0][1]);
    acc[0][2] = fmaf(a0, w.z, acc[0][2]); acc[0][3] = fmaf(a0, w.w, acc[0][3]);
    acc[1][0] = fmaf(a1, w.x, acc[1][0]); acc[1][1] = fmaf(a1, w.y, acc[1][1]);
    acc[1][2] = fmaf(a1, w.z, acc[1][2]); acc[1][3] = fmaf(a1, w.w, acc[1][3]);
    acc[2][0] = fmaf(a2, w.x, acc[2][0]); acc[2][1] = fmaf(a2, w.y, acc[2][1]);
    acc[2][2] = fmaf(a2, w.z, acc[2][2]); acc[2][3] = fmaf(a2, w.w, acc[2][3]);
    acc[3][0] = fmaf(a3, w.x, acc[3][0]); acc[3][1] = fmaf(a3, w.y, acc[3][1]);
    acc[3][2] = fmaf(a3, w.z, acc[3][2]); acc[3][3] = fmaf(a3, w.w, acc[3][3]);
  }

#pragma unroll
  for (int r = 0; r < 4; ++r) {
    int gr = row0 + ty * 4 + r;
    if (gr < M) {
      float4 o = make_float4(acc[r][0], acc[r][1], acc[r][2], acc[r][3]);
      reinterpret_cast<float4*>(C + (size_t)gr * N)[tx] = o;
    }
  }
}

// Wave-per-node aggregation, C=128: lane holds float2; 4-wide unrolled gather.
template <bool RELU>
__global__ __launch_bounds__(256) void agg128_kernel(
    const float* __restrict__ H, const float* __restrict__ bias,
    const int* __restrict__ offs, const int2* __restrict__ pairs,
    const float* __restrict__ dinv, float* __restrict__ out, int n) {
  int wave = (blockIdx.x << 2) | (threadIdx.x >> 6);
  int lane = threadIdx.x & 63;
  if (wave >= n) return;
  const int i = wave;
  const float2* H2 = reinterpret_cast<const float2*>(H);
  float2 acc = make_float2(0.f, 0.f);
  int j0 = offs[i], j1 = offs[i + 1];
  int j = j0;
  for (; j + 3 < j1; j += 4) {
    int2 p0 = pairs[j],   p1 = pairs[j+1], p2 = pairs[j+2], p3 = pairs[j+3];
    float2 h0 = H2[(size_t)p0.x * 64 + lane];
    float2 h1 = H2[(size_t)p1.x * 64 + lane];
    float2 h2 = H2[(size_t)p2.x * 64 + lane];
    float2 h3 = H2[(size_t)p3.x * 64 + lane];
    float w0 = __int_as_float(p0.y), w1 = __int_as_float(p1.y);
    float w2 = __int_as_float(p2.y), w3 = __int_as_float(p3.y);
    acc.x = fmaf(w0, h0.x, acc.x); acc.y = fmaf(w0, h0.y, acc.y);
    acc.x = fmaf(w1, h1.x, acc.x); acc.y = fmaf(w1, h1.y, acc.y);
    acc.x = fmaf(w2, h2.x, acc.x); acc.y = fmaf(w2, h2.y, acc.y);
    acc.x = fmaf(w3, h3.x, acc.x); acc.y = fmaf(w3, h3.y, acc.y);
  }
  for (; j < j1; ++j) {
    int2 p = pairs[j];
    float w = __int_as_float(p.y);
    float2 h = H2[(size_t)p.x * 64 + lane];
    acc.x = fmaf(w, h.x, acc.x); acc.y = fmaf(w, h.y, acc.y);
  }
  float di = dinv[i];
  float2 hs = H2[(size_t)i * 64 + lane];
  float2 b  = reinterpret_cast<const float2*>(bias)[lane];
  float2 o;
  o.x = fmaf(di, acc.x, di * di * hs.x) + b.x;
  o.y = fmaf(di, acc.y, di * di * hs.y) + b.y;
  if (RELU) { o.x = fmaxf(o.x, 0.f); o.y = fmaxf(o.y, 0.f); }
  reinterpret_cast<float2*>(out)[(size_t)i * 64 + lane] = o;
}

// Same, C=64: lane holds one float.
template <bool RELU>
__global__ __launch_bounds__(256) void agg64_kernel(
    const float* __restrict__ H, const float* __restrict__ bias,
    const int* __restrict__ offs, const int2* __restrict__ pairs,
    const float* __restrict__ dinv, float* __restrict__ out, int n) {
  int wave = (blockIdx.x << 2) | (threadIdx.x >> 6);
  int lane = threadIdx.x & 63;
  if (wave >= n) return;
  const int i = wave;
  float acc = 0.f;
  int j0 = offs[i], j1 = offs[i + 1];
  int j = j0;
  for (; j + 3 < j1; j += 4) {
    int2 p0 = pairs[j],   p1 = pairs[j+1], p2 = pairs[j+2], p3 = pairs[j+3];
    float h0 = H[(size_t)p0.x * 64 + lane];
    float h1 = H[(size_t)p1.x * 64 + lane];
    float h2 = H[(size_t)p2.x * 64 + lane];
    float h3 = H[(size_t)p3.x * 64 + lane];
    acc = fmaf(__int_as_float(p0.y), h0, acc);
    acc = fmaf(__int_as_float(p1.y), h1, acc);
    acc = fmaf(__int_as_float(p2.y), h2, acc);
    acc = fmaf(__int_as_float(p3.y), h3, acc);
  }
  for (; j < j1; ++j) {
    int2 p = pairs[j];
    acc = fmaf(__int_as_float(p.y), H[(size_t)p.x * 64 + lane], acc);
  }
  float di = dinv[i];
  float hs = H[(size_t)i * 64 + lane];
  float o  = fmaf(di, acc, di * di * hs) + bias[lane];
  if (RELU) o = fmaxf(o, 0.f);
  out[(size_t)i * 64 + lane] = o;
}

static inline size_t ws_align(size_t x) { return (x + 255) & ~(size_t)255; }

extern "C" void kernel_launch(void* const* d_in, const int* in_sizes, int n_in,
                              void* d_out, int out_size, void* d_ws, size_t ws_size,
                              hipStream_t stream) {
  const float* x  = (const float*)d_in[0];
  const int*   ei = (const int*)d_in[1];     // int32 per harness integer cast
  const float* ew = (const float*)d_in[2];
  const float* W1 = (const float*)d_in[3];
  const float* b1 = (const float*)d_in[4];
  const float* W2 = (const float*)d_in[5];
  const float* b2 = (const float*)d_in[6];
  float*       out = (float*)d_out;

  const int n = in_sizes[0] / 128;   // 50000
  const int E = in_sizes[2];         // 800000
  const int nb = (n + 255) / 256;    // scan blocks (196; must be <= 1024)

  char* ws = (char*)d_ws;
  size_t off = 0;
  auto alloc = [&](size_t bytes) -> char* {
    char* p = ws + off;
    off = ws_align(off + bytes);
    return p;
  };
  float* bufA   = (float*)alloc((size_t)n * 128 * sizeof(float)); // softmax out, later h1-agg
  float* bufB   = (float*)alloc((size_t)n * 128 * sizeof(float)); // h1, later h2
  char*  zbase  = ws + off;                                        // zeroed region
  int*   counts = (int*)  alloc((size_t)n * sizeof(int));
  size_t zbytes = (size_t)((ws + off) - zbase);
  float* dinv   = (float*)alloc((size_t)n * sizeof(float));
  int*   offs   = (int*)  alloc((size_t)(n + 1) * sizeof(int));
  int*   bsum   = (int*)  alloc((size_t)1024 * sizeof(int));
  int*   slot   = (int*)  alloc((size_t)E * sizeof(int));
  int2*  pairs  = (int2*) alloc((size_t)E * sizeof(int2));
  (void)ws_size; (void)n_in; (void)out_size;

  hipMemsetAsync(zbase, 0, zbytes, stream);

  // ---- CSR build ----
  count_kernel<<<(E + 255) / 256, 256, 0, stream>>>(ei, counts, slot, E);
  blocksum_kernel<<<nb, 256, 0, stream>>>(counts, bsum, n);
  blockscan_kernel<<<1, 1024, 0, stream>>>(bsum, nb, offs, n);
  blockwrite_kernel<<<nb, 256, 0, stream>>>(counts, bsum, offs, n);
  scatter_kernel<<<(E + 255) / 256, 256, 0, stream>>>(ei, ew, offs, slot, pairs, E);
  degseg_kernel<<<(n + 255) / 256, 256, 0, stream>>>(offs, pairs, dinv, n);
  scale_kernel<<<(E + 255) / 256, 256, 0, stream>>>(pairs, dinv, E);

  // ---- layer pipeline ----
  softmax_kernel<<<((size_t)n * 64 + 255) / 256, 256, 0, stream>>>(x, bufA, n);
  gemm_kernel<128><<<(n + 31) / 32, 256, 0, stream>>>(bufA, W1, bufB, n);       // h1 = s@W1
  agg128_kernel<true><<<(n + 3) / 4, 256, 0, stream>>>(bufB, b1, offs, pairs,
                                                       dinv, bufA, n);          // h1a
  gemm_kernel<64><<<(n + 63) / 64, 256, 0, stream>>>(bufA, W2, bufB, n);        // h2 = h1a@W2
  agg64_kernel<false><<<(n + 3) / 4, 256, 0, stream>>>(bufB, b2, offs, pairs,
                                                       dinv, out, n);
}

// Round 15
// 304.556 us; speedup vs baseline: 1.5802x; 1.0602x over previous
//
#include <hip/hip_runtime.h>
#include <math.h>

// ---------------------------------------------------------------------------
// 2-layer GCN:  out = GCN2( relu(GCN1( softmax(x) )) )
// out_i = dinv_i * sum_{e: col=i} (dinv[row]*ew) * h[row] + dinv_i^2 * h_i + b
// CSR grouped by destination rebuilt on-device each call.
// R9/R14: wave-per-node agg, ILP ladder: 1->4 gathers = 2.5->3.58 TB/s.
// R12: multi-block scan. R13: deg split. R14: atomic-free packed scatter.
// R15: (a) agg unroll 4x->8x (8 outstanding 512B gathers/wave);
//      (b) softmax fused into gemm128 A-staging (row softmax in LDS;
//          each row staged by exactly one block -> duplication-free).
// ---------------------------------------------------------------------------

// counts[col]++ ; slot[e] = old value (unique rank within destination)
__global__ void count_kernel(const int* __restrict__ ei, int* __restrict__ counts,
                             int* __restrict__ slot, int E) {
  int e = blockIdx.x * blockDim.x + threadIdx.x;
  if (e >= E) return;
  slot[e] = atomicAdd(&counts[ei[(size_t)E + e]], 1);
}

// --- multi-block scan, stage 1: per-block sum of counts ---
__global__ __launch_bounds__(256) void blocksum_kernel(
    const int* __restrict__ counts, int* __restrict__ blockSum, int n) {
  int i = blockIdx.x * 256 + threadIdx.x;
  int v = (i < n) ? counts[i] : 0;
  int s = v;
#pragma unroll
  for (int o = 32; o > 0; o >>= 1) s += __shfl_down(s, o);
  __shared__ int wsum[4];
  int wid = threadIdx.x >> 6, lane = threadIdx.x & 63;
  if (lane == 0) wsum[wid] = s;
  __syncthreads();
  if (threadIdx.x == 0)
    blockSum[blockIdx.x] = wsum[0] + wsum[1] + wsum[2] + wsum[3];
}

// --- stage 2: single-block exclusive scan of blockSum[nb] (nb <= 1024) ---
__global__ __launch_bounds__(1024) void blockscan_kernel(
    int* __restrict__ blockSum, int nb, int* __restrict__ offs, int n) {
  __shared__ int arr[1024];
  int t = threadIdx.x;
  int v = (t < nb) ? blockSum[t] : 0;
  arr[t] = v;
  __syncthreads();
  for (int d = 1; d < 1024; d <<= 1) {
    int u = (t >= d) ? arr[t - d] : 0;
    __syncthreads();
    arr[t] += u;
    __syncthreads();
  }
  if (t < nb) blockSum[t] = arr[t] - v;       // exclusive
  if (t == nb - 1) offs[n] = arr[t];          // grand total
}

// --- stage 3: in-block scan of counts + block offset -> offs[i] ---
__global__ __launch_bounds__(256) void blockwrite_kernel(
    const int* __restrict__ counts, const int* __restrict__ blockSum,
    int* __restrict__ offs, int n) {
  __shared__ int arr[256];
  int t = threadIdx.x;
  int i = blockIdx.x * 256 + t;
  int v = (i < n) ? counts[i] : 0;
  arr[t] = v;
  __syncthreads();
  for (int d = 1; d < 256; d <<= 1) {
    int u = (t >= d) ? arr[t - d] : 0;
    __syncthreads();
    arr[t] += u;
    __syncthreads();
  }
  if (i < n) offs[i] = blockSum[blockIdx.x] + arr[t] - v;  // exclusive
}

// pairs[offs[col]+slot[e]] = (row, ew)   -- NO atomics, one 8B random write
__global__ void scatter_kernel(const int* __restrict__ ei, const float* __restrict__ ew,
                               const int* __restrict__ offs, const int* __restrict__ slot,
                               int2* __restrict__ pairs, int E) {
  int e = blockIdx.x * blockDim.x + threadIdx.x;
  if (e >= E) return;
  int r = ei[e];
  int c = ei[(size_t)E + e];
  int pos = offs[c] + slot[e];
  pairs[pos] = make_int2(r, __float_as_int(ew[e]));
}

// deg_i = 1 + sum of pair.w over node i's segment (atomic-free); dinv = rsqrt
__global__ void degseg_kernel(const int* __restrict__ offs,
                              const int2* __restrict__ pairs,
                              float* __restrict__ dinv, int n) {
  int i = blockIdx.x * blockDim.x + threadIdx.x;
  if (i >= n) return;
  int j0 = offs[i], j1 = offs[i + 1];
  float d = 1.0f;                  // self loop weight
  for (int j = j0; j < j1; ++j) d += __int_as_float(pairs[j].y);
  dinv[i] = (d > 0.0f) ? (1.0f / sqrtf(d)) : 0.0f;
}

// pair.w *= dinv[pair.src]   (coalesced 8B RW + L2-resident dinv gather)
__global__ void scale_kernel(int2* __restrict__ pairs,
                             const float* __restrict__ dinv, int E) {
  int j = blockIdx.x * blockDim.x + threadIdx.x;
  if (j >= E) return;
  int2 p = pairs[j];
  p.y = __float_as_int(__int_as_float(p.y) * dinv[p.x]);
  pairs[j] = p;
}

// C = softmax_rows(X)(M x 128) @ W(128 x 128); softmax done in-LDS on the
// staged A tile (32 rows/block, 8 threads per row).
__global__ __launch_bounds__(256) void gemm128sm_kernel(
    const float* __restrict__ X, const float* __restrict__ W,
    float* __restrict__ C, int M) {
  constexpr int N   = 128;
  constexpr int CG  = N / 4;       // 32 float4 column groups
  constexpr int BM  = 32;          // rows per block
  constexpr int LDA = 132;
  __shared__ float sA[BM][LDA];
  const int t   = threadIdx.x;
  const int tx  = t % CG;
  const int ty  = t / CG;
  const int row0 = blockIdx.x * BM;

  for (int i = t; i < BM * 32; i += 256) {
    int r = i >> 5, c4 = i & 31;
    int gr = row0 + r;
    float4 v = make_float4(0.f, 0.f, 0.f, 0.f);
    if (gr < M) v = reinterpret_cast<const float4*>(X)[(size_t)gr * 32 + c4];
    *reinterpret_cast<float4*>(&sA[r][c4 * 4]) = v;
  }
  __syncthreads();

  // row softmax: 8 threads per row (lanes 8k..8k+7 of a wave share a row)
  {
    int r8 = t >> 3;            // row 0..31
    int l8 = t & 7;             // position within row group
    float m = -3.402823466e38f;
    for (int k = l8; k < 128; k += 8) m = fmaxf(m, sA[r8][k]);
#pragma unroll
    for (int o = 1; o < 8; o <<= 1) m = fmaxf(m, __shfl_xor(m, o));
    float s = 0.f;
    for (int k = l8; k < 128; k += 8) {
      float e = expf(sA[r8][k] - m);
      sA[r8][k] = e;
      s += e;
    }
#pragma unroll
    for (int o = 1; o < 8; o <<= 1) s += __shfl_xor(s, o);
    float inv = 1.0f / s;
    for (int k = l8; k < 128; k += 8) sA[r8][k] *= inv;
  }
  __syncthreads();

  float acc[4][4] = {};
#pragma unroll 4
  for (int k = 0; k < 128; ++k) {
    float4 w = reinterpret_cast<const float4*>(W + (size_t)k * N)[tx];
    float a0 = sA[ty * 4 + 0][k];
    float a1 = sA[ty * 4 + 1][k];
    float a2 = sA[ty * 4 + 2][k];
    float a3 = sA[ty * 4 + 3][k];
    acc[0][0] = fmaf(a0, w.x, acc[0][0]); acc[0][1] = fmaf(a0, w.y, acc[0][1]);
    acc[0][2] = fmaf(a0, w.z, acc[0][2]); acc[0][3] = fmaf(a0, w.w, acc[0][3]);
    acc[1][0] = fmaf(a1, w.x, acc[1][0]); acc[1][1] = fmaf(a1, w.y, acc[1][1]);
    acc[1][2] = fmaf(a1, w.z, acc[1][2]); acc[1][3] = fmaf(a1, w.w, acc[1][3]);
    acc[2][0] = fmaf(a2, w.x, acc[2][0]); acc[2][1] = fmaf(a2, w.y, acc[2][1]);
    acc[2][2] = fmaf(a2, w.z, acc[2][2]); acc[2][3] = fmaf(a2, w.w, acc[2][3]);
    acc[3][0] = fmaf(a3, w.x, acc[3][0]); acc[3][1] = fmaf(a3, w.y, acc[3][1]);
    acc[3][2] = fmaf(a3, w.z, acc[3][2]); acc[3][3] = fmaf(a3, w.w, acc[3][3]);
  }

#pragma unroll
  for (int r = 0; r < 4; ++r) {
    int gr = row0 + ty * 4 + r;
    if (gr < M) {
      float4 o = make_float4(acc[r][0], acc[r][1], acc[r][2], acc[r][3]);
      reinterpret_cast<float4*>(C + (size_t)gr * N)[tx] = o;
    }
  }
}

// C = A(M x 128) @ W(128 x 64), fp32, plain (layer 2)
__global__ __launch_bounds__(256) void gemm64_kernel(
    const float* __restrict__ A, const float* __restrict__ W,
    float* __restrict__ C, int M) {
  constexpr int N   = 64;
  constexpr int CG  = N / 4;       // 16
  constexpr int BM  = 64;
  constexpr int LDA = 132;
  __shared__ float sA[BM][LDA];
  const int t   = threadIdx.x;
  const int tx  = t % CG;
  const int ty  = t / CG;
  const int row0 = blockIdx.x * BM;

  for (int i = t; i < BM * 32; i += 256) {
    int r = i >> 5, c4 = i & 31;
    int gr = row0 + r;
    float4 v = make_float4(0.f, 0.f, 0.f, 0.f);
    if (gr < M) v = reinterpret_cast<const float4*>(A)[(size_t)gr * 32 + c4];
    *reinterpret_cast<float4*>(&sA[r][c4 * 4]) = v;
  }
  __syncthreads();

  float acc[4][4] = {};
#pragma unroll 4
  for (int k = 0; k < 128; ++k) {
    float4 w = reinterpret_cast<const float4*>(W + (size_t)k * N)[tx];
    float a0 = sA[ty * 4 + 0][k];
    float a1 = sA[ty * 4 + 1][k];
    float a2 = sA[ty * 4 + 2][k];
    float a3 = sA[ty * 4 + 3][k];
    acc[0][0] = fmaf(a0, w.x, acc[0][0]); acc[0][1] = fmaf(a0, w.y, acc[0][1]);
    acc[0][2] = fmaf(a0, w.z, acc[0][2]); acc[0][3] = fmaf(a0, w.w, acc[0][3]);
    acc[1][0] = fmaf(a1, w.x, acc[1][0]); acc[1][1] = fmaf(a1, w.y, acc[1][1]);
    acc[1][2] = fmaf(a1, w.z, acc[1][2]); acc[1][3] = fmaf(a1, w.w, acc[1][3]);
    acc[2][0] = fmaf(a2, w.x, acc[2][0]); acc[2][1] = fmaf(a2, w.y, acc[2][1]);
    acc[2][2] = fmaf(a2, w.z, acc[2][2]); acc[2][3] = fmaf(a2, w.w, acc[2][3]);
    acc[3][0] = fmaf(a3, w.x, acc[3][0]); acc[3][1] = fmaf(a3, w.y, acc[3][1]);
    acc[3][2] = fmaf(a3, w.z, acc[3][2]); acc[3][3] = fmaf(a3, w.w, acc[3][3]);
  }

#pragma unroll
  for (int r = 0; r < 4; ++r) {
    int gr = row0 + ty * 4 + r;
    if (gr < M) {
      float4 o = make_float4(acc[r][0], acc[r][1], acc[r][2], acc[r][3]);
      reinterpret_cast<float4*>(C + (size_t)gr * N)[tx] = o;
    }
  }
}

// Wave-per-node aggregation, C=128: lane holds float2; 8-wide unrolled gather.
template <bool RELU>
__global__ __launch_bounds__(256) void agg128_kernel(
    const float* __restrict__ H, const float* __restrict__ bias,
    const int* __restrict__ offs, const int2* __restrict__ pairs,
    const float* __restrict__ dinv, float* __restrict__ out, int n) {
  int wave = (blockIdx.x << 2) | (threadIdx.x >> 6);
  int lane = threadIdx.x & 63;
  if (wave >= n) return;
  const int i = wave;
  const float2* H2 = reinterpret_cast<const float2*>(H);
  float2 acc = make_float2(0.f, 0.f);
  int j0 = offs[i], j1 = offs[i + 1];
  int j = j0;
  for (; j + 7 < j1; j += 8) {
    int2 p0 = pairs[j],   p1 = pairs[j+1], p2 = pairs[j+2], p3 = pairs[j+3];
    int2 p4 = pairs[j+4], p5 = pairs[j+5], p6 = pairs[j+6], p7 = pairs[j+7];
    float2 h0 = H2[(size_t)p0.x * 64 + lane];
    float2 h1 = H2[(size_t)p1.x * 64 + lane];
    float2 h2 = H2[(size_t)p2.x * 64 + lane];
    float2 h3 = H2[(size_t)p3.x * 64 + lane];
    float2 h4 = H2[(size_t)p4.x * 64 + lane];
    float2 h5 = H2[(size_t)p5.x * 64 + lane];
    float2 h6 = H2[(size_t)p6.x * 64 + lane];
    float2 h7 = H2[(size_t)p7.x * 64 + lane];
    acc.x = fmaf(__int_as_float(p0.y), h0.x, acc.x); acc.y = fmaf(__int_as_float(p0.y), h0.y, acc.y);
    acc.x = fmaf(__int_as_float(p1.y), h1.x, acc.x); acc.y = fmaf(__int_as_float(p1.y), h1.y, acc.y);
    acc.x = fmaf(__int_as_float(p2.y), h2.x, acc.x); acc.y = fmaf(__int_as_float(p2.y), h2.y, acc.y);
    acc.x = fmaf(__int_as_float(p3.y), h3.x, acc.x); acc.y = fmaf(__int_as_float(p3.y), h3.y, acc.y);
    acc.x = fmaf(__int_as_float(p4.y), h4.x, acc.x); acc.y = fmaf(__int_as_float(p4.y), h4.y, acc.y);
    acc.x = fmaf(__int_as_float(p5.y), h5.x, acc.x); acc.y = fmaf(__int_as_float(p5.y), h5.y, acc.y);
    acc.x = fmaf(__int_as_float(p6.y), h6.x, acc.x); acc.y = fmaf(__int_as_float(p6.y), h6.y, acc.y);
    acc.x = fmaf(__int_as_float(p7.y), h7.x, acc.x); acc.y = fmaf(__int_as_float(p7.y), h7.y, acc.y);
  }
  for (; j + 3 < j1; j += 4) {
    int2 p0 = pairs[j],   p1 = pairs[j+1], p2 = pairs[j+2], p3 = pairs[j+3];
    float2 h0 = H2[(size_t)p0.x * 64 + lane];
    float2 h1 = H2[(size_t)p1.x * 64 + lane];
    float2 h2 = H2[(size_t)p2.x * 64 + lane];
    float2 h3 = H2[(size_t)p3.x * 64 + lane];
    acc.x = fmaf(__int_as_float(p0.y), h0.x, acc.x); acc.y = fmaf(__int_as_float(p0.y), h0.y, acc.y);
    acc.x = fmaf(__int_as_float(p1.y), h1.x, acc.x); acc.y = fmaf(__int_as_float(p1.y), h1.y, acc.y);
    acc.x = fmaf(__int_as_float(p2.y), h2.x, acc.x); acc.y = fmaf(__int_as_float(p2.y), h2.y, acc.y);
    acc.x = fmaf(__int_as_float(p3.y), h3.x, acc.x); acc.y = fmaf(__int_as_float(p3.y), h3.y, acc.y);
  }
  for (; j < j1; ++j) {
    int2 p = pairs[j];
    float w = __int_as_float(p.y);
    float2 h = H2[(size_t)p.x * 64 + lane];
    acc.x = fmaf(w, h.x, acc.x); acc.y = fmaf(w, h.y, acc.y);
  }
  float di = dinv[i];
  float2 hs = H2[(size_t)i * 64 + lane];
  float2 b  = reinterpret_cast<const float2*>(bias)[lane];
  float2 o;
  o.x = fmaf(di, acc.x, di * di * hs.x) + b.x;
  o.y = fmaf(di, acc.y, di * di * hs.y) + b.y;
  if (RELU) { o.x = fmaxf(o.x, 0.f); o.y = fmaxf(o.y, 0.f); }
  reinterpret_cast<float2*>(out)[(size_t)i * 64 + lane] = o;
}

// Same, C=64: lane holds one float; 8-wide unrolled gather.
template <bool RELU>
__global__ __launch_bounds__(256) void agg64_kernel(
    const float* __restrict__ H, const float* __restrict__ bias,
    const int* __restrict__ offs, const int2* __restrict__ pairs,
    const float* __restrict__ dinv, float* __restrict__ out, int n) {
  int wave = (blockIdx.x << 2) | (threadIdx.x >> 6);
  int lane = threadIdx.x & 63;
  if (wave >= n) return;
  const int i = wave;
  float acc = 0.f;
  int j0 = offs[i], j1 = offs[i + 1];
  int j = j0;
  for (; j + 7 < j1; j += 8) {
    int2 p0 = pairs[j],   p1 = pairs[j+1], p2 = pairs[j+2], p3 = pairs[j+3];
    int2 p4 = pairs[j+4], p5 = pairs[j+5], p6 = pairs[j+6], p7 = pairs[j+7];
    float h0 = H[(size_t)p0.x * 64 + lane];
    float h1 = H[(size_t)p1.x * 64 + lane];
    float h2 = H[(size_t)p2.x * 64 + lane];
    float h3 = H[(size_t)p3.x * 64 + lane];
    float h4 = H[(size_t)p4.x * 64 + lane];
    float h5 = H[(size_t)p5.x * 64 + lane];
    float h6 = H[(size_t)p6.x * 64 + lane];
    float h7 = H[(size_t)p7.x * 64 + lane];
    acc = fmaf(__int_as_float(p0.y), h0, acc);
    acc = fmaf(__int_as_float(p1.y), h1, acc);
    acc = fmaf(__int_as_float(p2.y), h2, acc);
    acc = fmaf(__int_as_float(p3.y), h3, acc);
    acc = fmaf(__int_as_float(p4.y), h4, acc);
    acc = fmaf(__int_as_float(p5.y), h5, acc);
    acc = fmaf(__int_as_float(p6.y), h6, acc);
    acc = fmaf(__int_as_float(p7.y), h7, acc);
  }
  for (; j + 3 < j1; j += 4) {
    int2 p0 = pairs[j],   p1 = pairs[j+1], p2 = pairs[j+2], p3 = pairs[j+3];
    float h0 = H[(size_t)p0.x * 64 + lane];
    float h1 = H[(size_t)p1.x * 64 + lane];
    float h2 = H[(size_t)p2.x * 64 + lane];
    float h3 = H[(size_t)p3.x * 64 + lane];
    acc = fmaf(__int_as_float(p0.y), h0, acc);
    acc = fmaf(__int_as_float(p1.y), h1, acc);
    acc = fmaf(__int_as_float(p2.y), h2, acc);
    acc = fmaf(__int_as_float(p3.y), h3, acc);
  }
  for (; j < j1; ++j) {
    int2 p = pairs[j];
    acc = fmaf(__int_as_float(p.y), H[(size_t)p.x * 64 + lane], acc);
  }
  float di = dinv[i];
  float hs = H[(size_t)i * 64 + lane];
  float o  = fmaf(di, acc, di * di * hs) + bias[lane];
  if (RELU) o = fmaxf(o, 0.f);
  out[(size_t)i * 64 + lane] = o;
}

static inline size_t ws_align(size_t x) { return (x + 255) & ~(size_t)255; }

extern "C" void kernel_launch(void* const* d_in, const int* in_sizes, int n_in,
                              void* d_out, int out_size, void* d_ws, size_t ws_size,
                              hipStream_t stream) {
  const float* x  = (const float*)d_in[0];
  const int*   ei = (const int*)d_in[1];     // int32 per harness integer cast
  const float* ew = (const float*)d_in[2];
  const float* W1 = (const float*)d_in[3];
  const float* b1 = (const float*)d_in[4];
  const float* W2 = (const float*)d_in[5];
  const float* b2 = (const float*)d_in[6];
  float*       out = (float*)d_out;

  const int n = in_sizes[0] / 128;   // 50000
  const int E = in_sizes[2];         // 800000
  const int nb = (n + 255) / 256;    // scan blocks (196; must be <= 1024)

  char* ws = (char*)d_ws;
  size_t off = 0;
  auto alloc = [&](size_t bytes) -> char* {
    char* p = ws + off;
    off = ws_align(off + bytes);
    return p;
  };
  float* bufA   = (float*)alloc((size_t)n * 128 * sizeof(float)); // h1a
  float* bufB   = (float*)alloc((size_t)n * 128 * sizeof(float)); // h1, later h2
  char*  zbase  = ws + off;                                        // zeroed region
  int*   counts = (int*)  alloc((size_t)n * sizeof(int));
  size_t zbytes = (size_t)((ws + off) - zbase);
  float* dinv   = (float*)alloc((size_t)n * sizeof(float));
  int*   offs   = (int*)  alloc((size_t)(n + 1) * sizeof(int));
  int*   bsum   = (int*)  alloc((size_t)1024 * sizeof(int));
  int*   slot   = (int*)  alloc((size_t)E * sizeof(int));
  int2*  pairs  = (int2*) alloc((size_t)E * sizeof(int2));
  (void)ws_size; (void)n_in; (void)out_size;

  hipMemsetAsync(zbase, 0, zbytes, stream);

  // ---- CSR build ----
  count_kernel<<<(E + 255) / 256, 256, 0, stream>>>(ei, counts, slot, E);
  blocksum_kernel<<<nb, 256, 0, stream>>>(counts, bsum, n);
  blockscan_kernel<<<1, 1024, 0, stream>>>(bsum, nb, offs, n);
  blockwrite_kernel<<<nb, 256, 0, stream>>>(counts, bsum, offs, n);
  scatter_kernel<<<(E + 255) / 256, 256, 0, stream>>>(ei, ew, offs, slot, pairs, E);
  degseg_kernel<<<(n + 255) / 256, 256, 0, stream>>>(offs, pairs, dinv, n);
  scale_kernel<<<(E + 255) / 256, 256, 0, stream>>>(pairs, dinv, E);

  // ---- layer pipeline ----
  gemm128sm_kernel<<<(n + 31) / 32, 256, 0, stream>>>(x, W1, bufB, n);   // h1 = softmax(x)@W1
  agg128_kernel<true><<<(n + 3) / 4, 256, 0, stream>>>(bufB, b1, offs, pairs,
                                                       dinv, bufA, n);   // h1a
  gemm64_kernel<<<(n + 63) / 64, 256, 0, stream>>>(bufA, W2, bufB, n);   // h2 = h1a@W2
  agg64_kernel<false><<<(n + 3) / 4, 256, 0, stream>>>(bufB, b2, offs, pairs,
                                                       dinv, out, n);
}